// Round 1
// baseline (151.142 us; speedup 1.0000x reference)
//
#include <hip/hip_runtime.h>
#include <hip/hip_fp16.h>
#include <stdint.h>

// BATCH=4096, LENGTH=128, FEAT=4, RANK=64, 126 mid sites.
#define NSITES 126
#define XP2 260   // xbuf row pitch (floats); buffer holds a 256-col half of x
#define VPH 72    // vbuf row pitch (halfs): 144B rows -> every c*VPH read is 16B-aligned,
                  // and bank coverage is perfectly uniform (8 word-accesses/bank per b128)

typedef _Float16 half8_t  __attribute__((ext_vector_type(8)));
typedef float    float4_t __attribute__((ext_vector_type(4)));

// light barrier: LDS-only drain; asm G-loads (vmcnt) stay in flight across it
#define LBAR() asm volatile("s_waitcnt lgkmcnt(0)\n\ts_barrier" ::: "memory")
// explicit wait: oldest loads complete when <=N remain outstanding
#define WAITV(N) asm volatile("s_waitcnt vmcnt(" #N ")" ::: "memory")
// zero-instruction tie: forces the 8 frag values through a volatile asm node,
// so MFMAs (pure ops) cannot be scheduled above the preceding WAITV
#define TIE8(F) asm volatile("" : "+v"(F[0]), "+v"(F[1]), "+v"(F[2]), "+v"(F[3]), \
                                  "+v"(F[4]), "+v"(F[5]), "+v"(F[6]), "+v"(F[7]))

// volatile asm load: compiler cannot sink/remat this; keeps vmcnt bookkeeping exact
__device__ __forceinline__ void aload(half8_t& d, const void* p) {
    asm volatile("global_load_dwordx4 %0, %1, off" : "=v"(d) : "v"(p));
}

// ---------------------------------------------------------------------------
// Repack mid_cores fp32 [126][64][4][64] -> fp16 B-fragments, frag F (16B):
// element j = G[l = 32h + 8q + j][i*64 + w*16 + c], lane = 16q + c,
// F = ((i*2+h)*4 + w)*64 + lane  (global index adds s*2048).
// Pure streaming gather: each 64B line of mid feeds exactly one fragment,
// so no LDS stage, no syncthreads, one thread per fragment. 1008 blocks.
// ---------------------------------------------------------------------------
__global__ __launch_bounds__(256) void repack_g(const float* __restrict__ mid,
                                                _Float16* __restrict__ gt) {
    const int F = blockIdx.x * 256 + threadIdx.x;          // 0..258047 == 126*2048
    const int lane = F & 63, w = (F >> 6) & 3, h = (F >> 8) & 1, i = (F >> 9) & 3;
    const int s = F >> 11;
    const int q = lane >> 4, c = lane & 15;
    const float* src = mid + (size_t)s * 16384 + (32 * h + 8 * q) * 256 + i * 64 + w * 16 + c;
    half8_t o;
#pragma unroll
    for (int j = 0; j < 8; ++j) o[j] = (_Float16)src[j * 256];
    ((half8_t*)gt)[F] = o;
}

// ---------------------------------------------------------------------------
// Main chain: 128 blocks x 256 threads, 32 batches/block as TWO groups of 16.
// Each wave owns r-cols [16w,16w+16) for BOTH groups: the 8 G fragments are
// loaded once per site and reused -> L2 G-traffic halves; the two groups are
// independent dependency chains -> ILP covers latency that 1 wave/SIMD can't.
// One lgkm-only barrier per site serves both groups. vbuf is fp16 (same
// rounding count as fp32-store+cvt: the MFMA A operand was fp16 anyway).
// ---------------------------------------------------------------------------
__global__ __launch_bounds__(256) void tt_chain(
    const float* __restrict__ x,      // [4096][128][4]
    const float* __restrict__ first,  // [4][64]
    const float* __restrict__ last,   // [64][4]
    const _Float16* __restrict__ gt,  // frag-ordered fp16, 32 KB/site
    float* __restrict__ out) {        // [4096]

    __shared__ __align__(16) _Float16 vbuf[2][2][16 * VPH];  // [group][pingpong]
    __shared__ __align__(16) float    xbuf[32 * XP2];        // 256-col window of x
    __shared__ int eacc[32];

    const int tid  = threadIdx.x;
    const int w    = tid >> 6;
    const int lane = tid & 63;
    const int q    = lane >> 4;
    const int c    = lane & 15;
    const int b0   = blockIdx.x * 32;

    // stage x cols 0..255 for all 32 rows (refilled with cols 256..511 at s==62)
    {
        const int bb = tid >> 3, seg = tid & 7;
        const float4_t* src = (const float4_t*)(x + (size_t)(b0 + bb) * 512) + seg;
        float4_t* dst = (float4_t*)(xbuf + bb * XP2) + seg;
#pragma unroll
        for (int k = 0; k < 8; ++k) dst[k * 8] = src[k * 8];
    }
    if (tid < 32) eacc[tid] = 0;
    __syncthreads();

    // v0[b,r] = sum_i x[b,0,i] * first[i,r]  (both groups)
    {
        const int bb = tid >> 4, rq = tid & 15;
#pragma unroll
        for (int g = 0; g < 2; ++g) {
            const int row = g * 16 + bb;
            const float xs0 = xbuf[row * XP2 + 0], xs1 = xbuf[row * XP2 + 1];
            const float xs2 = xbuf[row * XP2 + 2], xs3 = xbuf[row * XP2 + 3];
#pragma unroll
            for (int k = 0; k < 4; ++k) {
                const int r = rq * 4 + k;
                vbuf[g][0][bb * VPH + r] = (_Float16)(xs0 * first[r] + xs1 * first[64 + r] +
                                                      xs2 * first[128 + r] + xs3 * first[192 + r]);
            }
        }
    }

    // G register pipeline: per wave 8 frags/site at byte offset
    // s*32768 + ih*4096 + w*1024 + lane*16 ; shared by both batch groups.
    half8_t F0[8], F1[8], F2[8];
    const char* gbase = (const char*)gt + w * 1024 + lane * 16;
    auto LOAD = [&](int s, half8_t* F) {
        const char* p = gbase + (size_t)s * 32768;
#pragma unroll
        for (int ih = 0; ih < 8; ++ih) aload(F[ih], p + ih * 4096);
    };
    LOAD(0, F0);    // outstanding: 8
    LOAD(1, F1);    // outstanding: 16
    LBAR();         // vbuf[.][0] visible (lgkm only; G loads stay in flight)

    // one group's site step; g only feeds LDS addressing (no runtime-indexed regs)
    auto GSTEP = [&](int s, int p, half8_t* F, int g) {
        const _Float16* vr = &vbuf[g][p][c * VPH];
        half8_t af0 = *(const half8_t*)(vr + q * 8);        // A row=c, k=8q..8q+7
        half8_t af1 = *(const half8_t*)(vr + 32 + q * 8);   // k=32+8q..

        // wave-local per-batch power-of-2 renorm every 8 sites (f32 math, 1/8 sites)
        if ((s & 7) == 0 && s != 0) {
            float a[16];
#pragma unroll
            for (int k = 0; k < 8; ++k) { a[k] = (float)af0[k]; a[8 + k] = (float)af1[k]; }
            float m = 0.f;
#pragma unroll
            for (int k = 0; k < 16; ++k) m = fmaxf(m, fabsf(a[k]));
            m = fmaxf(m, __shfl_xor(m, 16));
            m = fmaxf(m, __shfl_xor(m, 32));
            int e = 0;
            if (m > 0.f) frexpf(m, &e);
            const float sc = ldexpf(1.0f, -e);
#pragma unroll
            for (int k = 0; k < 8; ++k) {
                af0[k] = (_Float16)(a[k] * sc);
                af1[k] = (_Float16)(a[8 + k] * sc);
            }
            if (tid < 16) eacc[g * 16 + tid] += e;   // wave 0, q==0: lane==c==batch
        }

        const int xcol = ((s + 1) * 4) & 255;        // cols wrap at the refill point
        float4_t xs[4];
#pragma unroll
        for (int jj = 0; jj < 4; ++jj)
            xs[jj] = *(const float4_t*)(xbuf + (g * 16 + q * 4 + jj) * XP2 + xcol);

        float4_t acc[4];
#pragma unroll
        for (int i = 0; i < 4; ++i) {
            float4_t z = {0.f, 0.f, 0.f, 0.f};
            z = __builtin_amdgcn_mfma_f32_16x16x32_f16(af0, F[i * 2 + 0], z, 0, 0, 0);
            z = __builtin_amdgcn_mfma_f32_16x16x32_f16(af1, F[i * 2 + 1], z, 0, 0, 0);
            acc[i] = z;
        }
        _Float16* wr = &vbuf[g][p ^ 1][0];
#pragma unroll
        for (int jj = 0; jj < 4; ++jj) {
            const float vn = xs[jj].x * acc[0][jj] + xs[jj].y * acc[1][jj] +
                             xs[jj].z * acc[2][jj] + xs[jj].w * acc[3][jj];
            wr[(q * 4 + jj) * VPH + w * 16 + c] = (_Float16)vn;   // C row=q*4+jj, col=w*16+c
        }
    };

    auto SITE = [&](int s, half8_t* F) {
        // invariant: 24 outstanding here; oldest 8 = this site's frags
        WAITV(16);
        TIE8(F);
        const int p = s & 1;
        GSTEP(s, p, F, 0);   // two independent chains: compiler interleaves for ILP
        GSTEP(s, p, F, 1);
        LBAR();              // one barrier serves both groups
    };

    for (int s = 0; s < NSITES; s += 3) {
        const int s2 = (s + 2 < NSITES) ? s + 2 : NSITES - 1;
        const int s3 = (s + 3 < NSITES) ? s + 3 : NSITES - 1;
        const int s4 = (s + 4 < NSITES) ? s + 4 : NSITES - 1;
        LOAD(s2, F2);          // every SITE is preceded by exactly one 8-load
        SITE(s, F0);
        LOAD(s3, F0);
        SITE(s + 1, F1);
        LOAD(s4, F1);
        SITE(s + 2, F2);
        if (s == 60) {
            // in-place refill: cols 256..511 overwrite local cols 0..255.
            // Sites <=62 (cols <=255) are fully consumed; site 63 reads local col 0.
            // Compiler-inserted vmcnt before the ds_writes may over-drain the asm
            // prefetch once (conservative -> correct); invariant self-restores.
            const int bb = tid >> 3, seg = tid & 7;
            const float4_t* src = (const float4_t*)(x + (size_t)(b0 + bb) * 512 + 256) + seg;
            float4_t* dst = (float4_t*)(xbuf + bb * XP2) + seg;
#pragma unroll
            for (int k = 0; k < 8; ++k) dst[k * 8] = src[k * 8];
            LBAR();
        }
    }
    WAITV(0);   // drain tail (clamped re-loads of site 125)

    // final v in vbuf[.][0] (126 even); out[b] = 2^eacc * sum_r v*last_vec
    {
        const int bb = tid >> 4, rq = tid & 15;
#pragma unroll
        for (int g = 0; g < 2; ++g) {
            const int row = g * 16 + bb;
            const float x0 = xbuf[row * XP2 + 252], x1 = xbuf[row * XP2 + 253];
            const float x2 = xbuf[row * XP2 + 254], x3 = xbuf[row * XP2 + 255];  // cols 508..511
            float dot = 0.f;
#pragma unroll
            for (int k = 0; k < 4; ++k) {
                const int r = rq * 4 + k;
                const float lv = last[r * 4 + 0] * x0 + last[r * 4 + 1] * x1 +
                                 last[r * 4 + 2] * x2 + last[r * 4 + 3] * x3;
                dot += lv * (float)vbuf[g][0][bb * VPH + r];
            }
#pragma unroll
            for (int o = 8; o > 0; o >>= 1) dot += __shfl_xor(dot, o, 16);
            if (rq == 0) out[b0 + row] = ldexpf(dot, eacc[g * 16 + bb]);
        }
    }
}

extern "C" void kernel_launch(void* const* d_in, const int* in_sizes, int n_in,
                              void* d_out, int out_size, void* d_ws, size_t ws_size,
                              hipStream_t stream) {
    (void)in_sizes; (void)n_in; (void)out_size; (void)ws_size;
    const float* x     = (const float*)d_in[0];
    const float* first = (const float*)d_in[1];
    const float* mid   = (const float*)d_in[2];
    const float* last  = (const float*)d_in[3];
    float* out = (float*)d_out;
    _Float16* gt = (_Float16*)d_ws;   // 126*2048*16 B = 4,128,768 B

    repack_g<<<1008, 256, 0, stream>>>(mid, gt);
    tt_chain<<<128, 256, 0, stream>>>(x, first, last, gt, out);
}